// Round 2
// baseline (2088.037 us; speedup 1.0000x reference)
//
#include <hip/hip_runtime.h>

#define S_LEN 2048
#define HID 64

__device__ __forceinline__ float rlane(float v, int l) {
    return __int_as_float(__builtin_amdgcn_readlane(__float_as_int(v), l));
}

__global__ __launch_bounds__(256) void rnn_garch_kernel(
    const float* __restrict__ res,   // (B, S)
    const float* __restrict__ Wih,   // (64, 2)
    const float* __restrict__ bih,   // (64,)
    const float* __restrict__ Whh,   // (64, 64)
    const float* __restrict__ bhh,   // (64,)
    const float* __restrict__ fcw,   // (64,)
    const float* __restrict__ fcb,   // (1,)
    float* __restrict__ out)         // (B, S)
{
    const int lane = threadIdx.x & 63;
    const int wave = threadIdx.x >> 6;
    const int b = blockIdx.x * 4 + wave;

    const float* __restrict__ row = res + (size_t)b * S_LEN;
    float* __restrict__ orow = out + (size_t)b * S_LEN;

    // ---- load weights: lane j holds row j of W_hh in 64 VGPRs ----
    float w[HID];
#pragma unroll
    for (int q = 0; q < 16; ++q) {
        const float4 v = *(const float4*)(Whh + lane * HID + q * 4);
        w[q * 4 + 0] = v.x; w[q * 4 + 1] = v.y;
        w[q * 4 + 2] = v.z; w[q * 4 + 3] = v.w;
    }
    const float wih0 = Wih[lane * 2 + 0];
    const float wih1 = Wih[lane * 2 + 1];
    const float basb = bih[lane] + bhh[lane];
    const float fw   = fcw[lane];
    const float fb   = fcb[0];

    // ---- sigma0 = var(row, ddof=1) ----
    float s1 = 0.f, s2 = 0.f;
#pragma unroll 8
    for (int i = 0; i < S_LEN / 64; ++i) {
        const float x = row[i * 64 + lane];
        s1 += x;
        s2 = fmaf(x, x, s2);
    }
#pragma unroll
    for (int off = 32; off > 0; off >>= 1) {
        s1 += __shfl_xor(s1, off, 64);
        s2 += __shfl_xor(s2, off, 64);
    }
    const float mean = s1 * (1.0f / S_LEN);
    float sigma = (s2 - s1 * mean) * (1.0f / (S_LEN - 1));

    float h = 0.f;
    float vout = (lane == 0) ? sigma : 0.f;   // out[b][0] = sigma0

    // eps double-buffer: 64 residuals per window, broadcast via readlane
    float epsc = row[lane];        // window 0: idx 0..63
    float epsn = row[64 + lane];   // window 1: idx 64..127

    for (int t = 1; t < S_LEN; ++t) {
        const int idx = (t - 1) & 63;
        if (idx == 0 && t > 1) {            // wave-uniform
            epsc = epsn;
            const int nb = ((t - 1) >> 6) + 1;
            if (nb < S_LEN / 64) epsn = row[nb * 64 + lane];
        }
        const float ep = rlane(epsc, idx);
        const float e2 = ep * ep;

        float a0 = fmaf(e2, wih0, basb);
        a0 = fmaf(sigma, wih1, a0);
        float a1 = 0.f, a2 = 0.f, a3 = 0.f;
#pragma unroll
        for (int k = 0; k < HID; k += 4) {
            a0 = fmaf(w[k + 0], rlane(h, k + 0), a0);
            a1 = fmaf(w[k + 1], rlane(h, k + 1), a1);
            a2 = fmaf(w[k + 2], rlane(h, k + 2), a2);
            a3 = fmaf(w[k + 3], rlane(h, k + 3), a3);
        }
        h = (a0 + a1) + (a2 + a3);

        // x = fc . h + fc_b  (butterfly: every lane gets the total)
        float p = fw * h;
#pragma unroll
        for (int off = 32; off > 0; off >>= 1) p += __shfl_xor(p, off, 64);
        const float x = p + fb;

        // softplus(x) = max(x,0) + log1p(exp(-|x|))
        const float ax = fabsf(x);
        const float sp = fmaxf(x, 0.f) + log1pf(expf(-ax));
        sigma = sp + 1e-6f;

        // stage sigma_t into lane (t&63); coalesced store each 64 steps
        if ((t & 63) == lane) vout = sigma;
        if ((t & 63) == 63) orow[(t - 63) + lane] = vout;
    }
}

extern "C" void kernel_launch(void* const* d_in, const int* in_sizes, int n_in,
                              void* d_out, int out_size, void* d_ws, size_t ws_size,
                              hipStream_t stream) {
    const float* res = (const float*)d_in[0];
    const float* Wih = (const float*)d_in[1];
    const float* bih = (const float*)d_in[2];
    const float* Whh = (const float*)d_in[3];
    const float* bhh = (const float*)d_in[4];
    const float* fcw = (const float*)d_in[5];
    const float* fcb = (const float*)d_in[6];
    float* out = (float*)d_out;

    const int B = 2048;
    dim3 grid(B / 4), block(256);
    hipLaunchKernelGGL(rnn_garch_kernel, grid, block, 0, stream,
                       res, Wih, bih, Whh, bhh, fcw, fcb, out);
}

// Round 3
// 1592.624 us; speedup vs baseline: 1.3111x; 1.3111x over previous
//
#include <hip/hip_runtime.h>

#define S_LEN 2048
#define HID 64

__device__ __forceinline__ float rlane(float v, int l) {
    return __int_as_float(__builtin_amdgcn_readlane(__float_as_int(v), l));
}

// sum across 64 lanes -> uniform scalar in all lanes.
// 5 x ds_swizzle (xor within 32-lane halves) + 2 x v_readlane cross-half.
__device__ __forceinline__ float wave_sum(float v) {
    v += __int_as_float(__builtin_amdgcn_ds_swizzle(__float_as_int(v), (1 << 10) | 0x1F));
    v += __int_as_float(__builtin_amdgcn_ds_swizzle(__float_as_int(v), (2 << 10) | 0x1F));
    v += __int_as_float(__builtin_amdgcn_ds_swizzle(__float_as_int(v), (4 << 10) | 0x1F));
    v += __int_as_float(__builtin_amdgcn_ds_swizzle(__float_as_int(v), (8 << 10) | 0x1F));
    v += __int_as_float(__builtin_amdgcn_ds_swizzle(__float_as_int(v), (16 << 10) | 0x1F));
    return rlane(v, 0) + rlane(v, 32);
}

__global__ __launch_bounds__(256, 1) void rnn_garch_kernel(
    const float* __restrict__ res,   // (B, S)
    const float* __restrict__ Wih,   // (64, 2)
    const float* __restrict__ bih,   // (64,)
    const float* __restrict__ Whh,   // (64, 64)
    const float* __restrict__ bhh,   // (64,)
    const float* __restrict__ fcw,   // (64,)
    const float* __restrict__ fcb,   // (1,)
    float* __restrict__ out)         // (B, S)
{
    const int lane = threadIdx.x & 63;
    const int wave = threadIdx.x >> 6;
    const int b = blockIdx.x * 4 + wave;

    const float* __restrict__ row = res + (size_t)b * S_LEN;
    float* __restrict__ orow = out + (size_t)b * S_LEN;

    // lane j holds row j of W_hh in 64 VGPRs (launch_bounds(256,1) -> no spill)
    float w[HID];
#pragma unroll
    for (int q = 0; q < 16; ++q) {
        const float4 v = *(const float4*)(Whh + lane * HID + q * 4);
        w[q * 4 + 0] = v.x; w[q * 4 + 1] = v.y;
        w[q * 4 + 2] = v.z; w[q * 4 + 3] = v.w;
    }
    const float wih0 = Wih[lane * 2 + 0];
    const float wih1 = Wih[lane * 2 + 1];
    const float basb = bih[lane] + bhh[lane];
    const float fw   = fcw[lane];
    const float fb   = fcb[0];

    // ---- sigma0 = var(row, ddof=1) ----
    float s1 = 0.f, s2 = 0.f;
#pragma unroll 8
    for (int i = 0; i < S_LEN / 64; ++i) {
        const float x = row[i * 64 + lane];
        s1 += x;
        s2 = fmaf(x, x, s2);
    }
    s1 = wave_sum(s1);
    s2 = wave_sum(s2);
    const float mean = s1 * (1.0f / S_LEN);
    float sigma = (s2 - s1 * mean) * (1.0f / (S_LEN - 1));

    float h = 0.f;
    float vout = (lane == 0) ? sigma : 0.f;   // out[b][0] = sigma0

    // eps^2 double-buffer: squared once per 64-step window, broadcast via readlane
    float ec = row[lane];
    float en = row[64 + lane];
    float eq = ec * ec;          // window 0 squared

    for (int t = 1; t < S_LEN; ++t) {
        const int idx = (t - 1) & 63;
        if (idx == 0 && t > 1) {            // wave-uniform window advance
            eq = en * en;
            const int nb = ((t - 1) >> 6) + 1;
            if (nb < S_LEN / 64) en = row[nb * 64 + lane];
        }
        const float e2 = rlane(eq, idx);

        float a0 = fmaf(e2, wih0, basb);
        float a1 = 0.f, a2 = 0.f, a3 = 0.f;
#pragma unroll
        for (int k = 0; k < HID; k += 4) {
            a0 = fmaf(w[k + 0], rlane(h, k + 0), a0);
            a1 = fmaf(w[k + 1], rlane(h, k + 1), a1);
            a2 = fmaf(w[k + 2], rlane(h, k + 2), a2);
            a3 = fmaf(w[k + 3], rlane(h, k + 3), a3);
        }
        // sigma (prev step) enters last -> its reduce/softplus chain hides
        // under the 64-fma issue above
        h = fmaf(sigma, wih1, (a0 + a1) + (a2 + a3));

        // x = fc . h + fc_b  (uniform scalar in all lanes)
        const float x = wave_sum(fw * h) + fb;

        // softplus(x) = max(x,0) + log(1 + exp(-|x|)) via v_exp/v_log
        const float e  = __expf(-fabsf(x));
        sigma = fmaxf(x, 0.f) + __logf(1.0f + e) + 1e-6f;

        // stage sigma_t into lane (t&63); coalesced store each 64 steps
        if ((t & 63) == lane) vout = sigma;
        if ((t & 63) == 63) orow[(t - 63) + lane] = vout;
    }
}

extern "C" void kernel_launch(void* const* d_in, const int* in_sizes, int n_in,
                              void* d_out, int out_size, void* d_ws, size_t ws_size,
                              hipStream_t stream) {
    const float* res = (const float*)d_in[0];
    const float* Wih = (const float*)d_in[1];
    const float* bih = (const float*)d_in[2];
    const float* Whh = (const float*)d_in[3];
    const float* bhh = (const float*)d_in[4];
    const float* fcw = (const float*)d_in[5];
    const float* fcb = (const float*)d_in[6];
    float* out = (float*)d_out;

    const int B = 2048;
    dim3 grid(B / 4), block(256);
    hipLaunchKernelGGL(rnn_garch_kernel, grid, block, 0, stream,
                       res, Wih, bih, Whh, bhh, fcw, fcb, out);
}

// Round 4
// 1377.198 us; speedup vs baseline: 1.5161x; 1.1564x over previous
//
#include <hip/hip_runtime.h>

#define S_LEN 2048
#define HID 64

typedef float f32x4 __attribute__((ext_vector_type(4)));

__device__ __forceinline__ float rlane(float v, int l) {
    return __int_as_float(__builtin_amdgcn_readlane(__float_as_int(v), l));
}

// v += dpp_moved(v); CTRL/RM compile-time. bound_ctrl=1 -> OOB lanes read 0.
template<int CTRL, int RM>
__device__ __forceinline__ float dpp_add(float v) {
    int t = __builtin_amdgcn_update_dpp(0, __float_as_int(v), CTRL, RM, 0xF, true);
    return v + __int_as_float(t);
}

// sum across 64 lanes -> uniform scalar (valid in all lanes), VALU-only.
__device__ __forceinline__ float wave_sum(float v) {
    v = dpp_add<0x111, 0xF>(v);  // row_shr:1
    v = dpp_add<0x112, 0xF>(v);  // row_shr:2
    v = dpp_add<0x114, 0xF>(v);  // row_shr:4
    v = dpp_add<0x118, 0xF>(v);  // row_shr:8  -> lane15/31/47/63 hold row sums
    v = dpp_add<0x142, 0xA>(v);  // row_bcast:15 -> lane31,63 hold half sums
    v = dpp_add<0x143, 0xC>(v);  // row_bcast:31 -> lane63 holds total
    return rlane(v, 63);
}

__global__ __launch_bounds__(256, 1) void rnn_garch_kernel(
    const float* __restrict__ res,   // (B, S)
    const float* __restrict__ Wih,   // (64, 2)
    const float* __restrict__ bih,   // (64,)
    const float* __restrict__ Whh,   // (64, 64)
    const float* __restrict__ bhh,   // (64,)
    const float* __restrict__ fcw,   // (64,)
    const float* __restrict__ fcb,   // (1,)
    float* __restrict__ out)         // (B, S)
{
    const int lane = threadIdx.x & 63;
    const int wave = threadIdx.x >> 6;
    const int b = blockIdx.x * 4 + wave;

    const float* __restrict__ row = res + (size_t)b * S_LEN;
    float* __restrict__ orow = out + (size_t)b * S_LEN;

    // lane j holds row j of W_hh in 16 x float4 = 64 VGPRs
    const f32x4* wr = (const f32x4*)(Whh + lane * HID);
    f32x4 w0 = wr[0],  w1 = wr[1],  w2 = wr[2],  w3 = wr[3];
    f32x4 w4 = wr[4],  w5 = wr[5],  w6 = wr[6],  w7 = wr[7];
    f32x4 w8 = wr[8],  w9 = wr[9],  w10 = wr[10], w11 = wr[11];
    f32x4 w12 = wr[12], w13 = wr[13], w14 = wr[14], w15 = wr[15];
    // Pin: values become opaque to the compiler -> it cannot re-load them
    // from memory inside the loop; they stay VGPR-resident.
    asm("" : "+v"(w0), "+v"(w1), "+v"(w2), "+v"(w3),
             "+v"(w4), "+v"(w5), "+v"(w6), "+v"(w7),
             "+v"(w8), "+v"(w9), "+v"(w10), "+v"(w11),
             "+v"(w12), "+v"(w13), "+v"(w14), "+v"(w15));

    const float wih0 = Wih[lane * 2 + 0];
    const float wih1 = Wih[lane * 2 + 1];
    const float basb = bih[lane] + bhh[lane];
    const float fw   = fcw[lane];
    const float fb   = fcb[0];

    // ---- sigma0 = var(row, ddof=1) ----
    float s1 = 0.f, s2 = 0.f;
#pragma unroll 8
    for (int i = 0; i < S_LEN / 64; ++i) {
        const float x = row[i * 64 + lane];
        s1 += x;
        s2 = fmaf(x, x, s2);
    }
    s1 = wave_sum(s1);
    s2 = wave_sum(s2);
    const float mean = s1 * (1.0f / S_LEN);
    float sigma = (s2 - s1 * mean) * (1.0f / (S_LEN - 1));

    float h = 0.f;
    float vout = (lane == 0) ? sigma : 0.f;   // out[b][0] = sigma0

    // eps^2 double-buffer: squared once per 64-step window, broadcast via readlane
    float en = row[64 + lane];
    float eq = row[lane] * row[lane];

#define MV4(W, K) \
    a0 = fmaf(W.x, rlane(h, K + 0), a0); \
    a1 = fmaf(W.y, rlane(h, K + 1), a1); \
    a2 = fmaf(W.z, rlane(h, K + 2), a2); \
    a3 = fmaf(W.w, rlane(h, K + 3), a3);

#pragma unroll 2
    for (int t = 1; t < S_LEN; ++t) {
        const int idx = (t - 1) & 63;
        if (idx == 0 && t > 1) {            // wave-uniform window advance
            eq = en * en;
            const int nb = ((t - 1) >> 6) + 1;
            if (nb < S_LEN / 64) en = row[nb * 64 + lane];
        }
        const float e2 = rlane(eq, idx);

        float a0 = fmaf(e2, wih0, basb);
        float a1 = 0.f, a2 = 0.f, a3 = 0.f;
        MV4(w0, 0)   MV4(w1, 4)   MV4(w2, 8)   MV4(w3, 12)
        MV4(w4, 16)  MV4(w5, 20)  MV4(w6, 24)  MV4(w7, 28)
        MV4(w8, 32)  MV4(w9, 36)  MV4(w10, 40) MV4(w11, 44)
        MV4(w12, 48) MV4(w13, 52) MV4(w14, 56) MV4(w15, 60)
        // sigma (prev step) enters last -> its chain hides under the fma issue
        h = fmaf(sigma, wih1, (a0 + a1) + (a2 + a3));

        // x = fc . h + fc_b  (uniform scalar in all lanes)
        const float x = wave_sum(fw * h) + fb;

        // softplus(x) = max(x,0) + log(1 + exp(-|x|)) via v_exp/v_log
        const float e = __expf(-fabsf(x));
        sigma = fmaxf(x, 0.f) + __logf(1.0f + e) + 1e-6f;

        // stage sigma_t into lane (t&63); coalesced store each 64 steps
        if ((t & 63) == lane) vout = sigma;
        if ((t & 63) == 63) orow[(t - 63) + lane] = vout;
    }
#undef MV4
}

extern "C" void kernel_launch(void* const* d_in, const int* in_sizes, int n_in,
                              void* d_out, int out_size, void* d_ws, size_t ws_size,
                              hipStream_t stream) {
    const float* res = (const float*)d_in[0];
    const float* Wih = (const float*)d_in[1];
    const float* bih = (const float*)d_in[2];
    const float* Whh = (const float*)d_in[3];
    const float* bhh = (const float*)d_in[4];
    const float* fcw = (const float*)d_in[5];
    const float* fcb = (const float*)d_in[6];
    float* out = (float*)d_out;

    const int B = 2048;
    dim3 grid(B / 4), block(256);
    hipLaunchKernelGGL(rnn_garch_kernel, grid, block, 0, stream,
                       res, Wih, bih, Whh, bhh, fcw, fcb, out);
}

// Round 5
// 979.683 us; speedup vs baseline: 2.1313x; 1.4058x over previous
//
#include <hip/hip_runtime.h>

#define S_LEN 2048
#define HID 64

typedef float f32x4 __attribute__((ext_vector_type(4)));

__device__ __forceinline__ float rlane(float v, int l) {
    return __int_as_float(__builtin_amdgcn_readlane(__float_as_int(v), l));
}

// v += dpp_moved(v); CTRL/RM compile-time. bound_ctrl=1 -> OOB lanes read 0.
template<int CTRL, int RM>
__device__ __forceinline__ float dpp_add(float v) {
    int t = __builtin_amdgcn_update_dpp(0, __float_as_int(v), CTRL, RM, 0xF, true);
    return v + __int_as_float(t);
}

// sum across 64 lanes -> uniform scalar, VALU-only.
__device__ __forceinline__ float wave_sum(float v) {
    v = dpp_add<0x111, 0xF>(v);  // row_shr:1
    v = dpp_add<0x112, 0xF>(v);  // row_shr:2
    v = dpp_add<0x114, 0xF>(v);  // row_shr:4
    v = dpp_add<0x118, 0xF>(v);  // row_shr:8
    v = dpp_add<0x142, 0xA>(v);  // row_bcast:15
    v = dpp_add<0x143, 0xC>(v);  // row_bcast:31 -> lane63 holds total
    return rlane(v, 63);
}

__global__ __launch_bounds__(256, 1) void rnn_garch_kernel(
    const float* __restrict__ res,   // (B, S)
    const float* __restrict__ Wih,   // (64, 2)
    const float* __restrict__ bih,   // (64,)
    const float* __restrict__ Whh,   // (64, 64)
    const float* __restrict__ bhh,   // (64,)
    const float* __restrict__ fcw,   // (64,)
    const float* __restrict__ fcb,   // (1,)
    float* __restrict__ out)         // (B, S)
{
    const int lane = threadIdx.x & 63;
    const int wave = threadIdx.x >> 6;
    const int b = blockIdx.x * 4 + wave;

    const float* __restrict__ row = res + (size_t)b * S_LEN;
    float* __restrict__ orow = out + (size_t)b * S_LEN;

    // per-wave h broadcast buffer (wave-private region; no cross-wave sync)
    __shared__ __align__(16) float hb[4][HID];

    // lane j holds row j of W_hh in 16 x float4 = 64 regs (VGPR or AGPR)
    const f32x4* wr = (const f32x4*)(Whh + lane * HID);
    f32x4 w0 = wr[0],  w1 = wr[1],  w2 = wr[2],  w3 = wr[3];
    f32x4 w4 = wr[4],  w5 = wr[5],  w6 = wr[6],  w7 = wr[7];
    f32x4 w8 = wr[8],  w9 = wr[9],  w10 = wr[10], w11 = wr[11];
    f32x4 w12 = wr[12], w13 = wr[13], w14 = wr[14], w15 = wr[15];
    // Pin: opaque to the compiler -> cannot be re-loaded from memory in-loop.
    asm("" : "+v"(w0), "+v"(w1), "+v"(w2), "+v"(w3),
             "+v"(w4), "+v"(w5), "+v"(w6), "+v"(w7),
             "+v"(w8), "+v"(w9), "+v"(w10), "+v"(w11),
             "+v"(w12), "+v"(w13), "+v"(w14), "+v"(w15));

    const float wih0 = Wih[lane * 2 + 0];
    const float wih1 = Wih[lane * 2 + 1];
    const float basb = bih[lane] + bhh[lane];
    const float fw   = fcw[lane];
    const float fb   = fcb[0];

    // ---- sigma0 = var(row, ddof=1) ----
    float s1 = 0.f, s2 = 0.f;
#pragma unroll 8
    for (int i = 0; i < S_LEN / 64; ++i) {
        const float x = row[i * 64 + lane];
        s1 += x;
        s2 = fmaf(x, x, s2);
    }
    s1 = wave_sum(s1);
    s2 = wave_sum(s2);
    const float mean = s1 * (1.0f / S_LEN);
    float sigma = (s2 - s1 * mean) * (1.0f / (S_LEN - 1));

    float h = 0.f;
    float vout = (lane == 0) ? sigma : 0.f;   // out[b][0] = sigma0

    // eps^2 double-buffer: squared once per 64-step window
    float en = row[64 + lane];
    float eq = row[lane] * row[lane];

    const f32x4* hb4 = (const f32x4*)&hb[wave][0];
    float* hbw = &hb[wave][0];

#define MV4(Q, W) { const f32x4 hv = hb4[Q]; \
    a0 = fmaf(W.x, hv.x, a0); \
    a1 = fmaf(W.y, hv.y, a1); \
    a2 = fmaf(W.z, hv.z, a2); \
    a3 = fmaf(W.w, hv.w, a3); }

#pragma unroll 4
    for (int t = 1; t < S_LEN; ++t) {
        const int idx = (t - 1) & 63;
        if (idx == 0 && t > 1) {            // wave-uniform window advance
            eq = en * en;
            const int nb = ((t - 1) >> 6) + 1;
            if (nb < S_LEN / 64) en = row[nb * 64 + lane];
        }

        hbw[lane] = h;                      // ds_write_b32 (wave-private)
        const float e2 = rlane(eq, idx);

        float a0 = fmaf(e2, wih0, basb);
        float a1 = 0.f, a2 = 0.f, a3 = 0.f;
        MV4(0, w0)   MV4(1, w1)   MV4(2, w2)   MV4(3, w3)
        MV4(4, w4)   MV4(5, w5)   MV4(6, w6)   MV4(7, w7)
        MV4(8, w8)   MV4(9, w9)   MV4(10, w10) MV4(11, w11)
        MV4(12, w12) MV4(13, w13) MV4(14, w14) MV4(15, w15)
        h = fmaf(sigma, wih1, (a0 + a1) + (a2 + a3));

        // x = fc . h + fc_b  (uniform scalar in all lanes)
        const float x = wave_sum(fw * h) + fb;

        // softplus(x) = max(x,0) + log(1 + exp(-|x|)) via v_exp/v_log
        const float e = __expf(-fabsf(x));
        sigma = fmaxf(x, 0.f) + __logf(1.0f + e) + 1e-6f;

        // stage sigma_t into lane (t&63); coalesced store each 64 steps
        if ((t & 63) == lane) vout = sigma;
        if ((t & 63) == 63) orow[(t - 63) + lane] = vout;
    }
#undef MV4
}

extern "C" void kernel_launch(void* const* d_in, const int* in_sizes, int n_in,
                              void* d_out, int out_size, void* d_ws, size_t ws_size,
                              hipStream_t stream) {
    const float* res = (const float*)d_in[0];
    const float* Wih = (const float*)d_in[1];
    const float* bih = (const float*)d_in[2];
    const float* Whh = (const float*)d_in[3];
    const float* bhh = (const float*)d_in[4];
    const float* fcw = (const float*)d_in[5];
    const float* fcb = (const float*)d_in[6];
    float* out = (float*)d_out;

    const int B = 2048;
    dim3 grid(B / 4), block(256);
    hipLaunchKernelGGL(rnn_garch_kernel, grid, block, 0, stream,
                       res, Wih, bih, Whh, bhh, fcw, fcb, out);
}

// Round 6
// 929.146 us; speedup vs baseline: 2.2473x; 1.0544x over previous
//
#include <hip/hip_runtime.h>

#define S_LEN 2048
#define HID 64

typedef float f32x4 __attribute__((ext_vector_type(4)));
typedef float f32x2 __attribute__((ext_vector_type(2)));

__device__ __forceinline__ float rlane(float v, int l) {
    return __int_as_float(__builtin_amdgcn_readlane(__float_as_int(v), l));
}

__device__ __forceinline__ f32x2 lo2(f32x4 v) { return __builtin_shufflevector(v, v, 0, 1); }
__device__ __forceinline__ f32x2 hi2(f32x4 v) { return __builtin_shufflevector(v, v, 2, 3); }

// v += dpp_moved(v); CTRL/RM compile-time. bound_ctrl=1 -> OOB lanes read 0.
template<int CTRL, int RM>
__device__ __forceinline__ float dpp_add(float v) {
    int t = __builtin_amdgcn_update_dpp(0, __float_as_int(v), CTRL, RM, 0xF, true);
    return v + __int_as_float(t);
}

// sum across 64 lanes -> uniform scalar, VALU-only.
__device__ __forceinline__ float wave_sum(float v) {
    v = dpp_add<0x111, 0xF>(v);  // row_shr:1
    v = dpp_add<0x112, 0xF>(v);  // row_shr:2
    v = dpp_add<0x114, 0xF>(v);  // row_shr:4
    v = dpp_add<0x118, 0xF>(v);  // row_shr:8
    v = dpp_add<0x142, 0xA>(v);  // row_bcast:15
    v = dpp_add<0x143, 0xC>(v);  // row_bcast:31 -> lane63 holds total
    return rlane(v, 63);
}

__global__ __launch_bounds__(256, 1) void rnn_garch_kernel(
    const float* __restrict__ res,   // (B, S)
    const float* __restrict__ Wih,   // (64, 2)
    const float* __restrict__ bih,   // (64,)
    const float* __restrict__ Whh,   // (64, 64)
    const float* __restrict__ bhh,   // (64,)
    const float* __restrict__ fcw,   // (64,)
    const float* __restrict__ fcb,   // (1,)
    float* __restrict__ out)         // (B, S)
{
    const int lane = threadIdx.x & 63;
    const int wave = threadIdx.x >> 6;
    const int b = blockIdx.x * 4 + wave;

    const float* __restrict__ row = res + (size_t)b * S_LEN;
    float* __restrict__ orow = out + (size_t)b * S_LEN;

    // per-wave h broadcast buffer (wave-private region; no cross-wave sync)
    __shared__ __align__(16) float hb[4][HID];

    // lane j holds row j of W_hh in 16 x float4 = 64 regs
    const f32x4* wr = (const f32x4*)(Whh + lane * HID);
    f32x4 w0 = wr[0],  w1 = wr[1],  w2 = wr[2],  w3 = wr[3];
    f32x4 w4 = wr[4],  w5 = wr[5],  w6 = wr[6],  w7 = wr[7];
    f32x4 w8 = wr[8],  w9 = wr[9],  w10 = wr[10], w11 = wr[11];
    f32x4 w12 = wr[12], w13 = wr[13], w14 = wr[14], w15 = wr[15];
    // Pin: opaque to the compiler -> cannot be re-loaded from memory in-loop.
    asm("" : "+v"(w0), "+v"(w1), "+v"(w2), "+v"(w3),
             "+v"(w4), "+v"(w5), "+v"(w6), "+v"(w7),
             "+v"(w8), "+v"(w9), "+v"(w10), "+v"(w11),
             "+v"(w12), "+v"(w13), "+v"(w14), "+v"(w15));

    const float wih0 = Wih[lane * 2 + 0];
    const float wih1 = Wih[lane * 2 + 1];
    const float basb = bih[lane] + bhh[lane];
    const float fw   = fcw[lane];
    const float fb   = fcb[0];

    // ---- sigma0 = var(row, ddof=1) ----
    float s1 = 0.f, s2 = 0.f;
#pragma unroll 8
    for (int i = 0; i < S_LEN / 64; ++i) {
        const float x = row[i * 64 + lane];
        s1 += x;
        s2 = fmaf(x, x, s2);
    }
    s1 = wave_sum(s1);
    s2 = wave_sum(s2);
    const float mean = s1 * (1.0f / S_LEN);
    float sigma = (s2 - s1 * mean) * (1.0f / (S_LEN - 1));

    float vout = (lane == 0) ? sigma : 0.f;   // out[b][0] = sigma0

    // eps^2 double-buffer: squared once per 64-step window
    float en = row[64 + lane];
    float eq = row[lane] * row[lane];

    const f32x4* hb4 = (const f32x4*)&hb[wave][0];
    float* hbw = &hb[wave][0];
    hbw[lane] = 0.f;                 // h_0 = 0

// two packed fmas per weight quad; pairs are free sub-registers
#define MV4(Q, W, AL, AH) { const f32x4 hv = hb4[Q]; \
    AL = __builtin_elementwise_fma(lo2(W), lo2(hv), AL); \
    AH = __builtin_elementwise_fma(hi2(W), hi2(hv), AH); }

#pragma unroll 2
    for (int t = 1; t < S_LEN; ++t) {
        const int idx = (t - 1) & 63;
        if (idx == 0 && t > 1) {            // wave-uniform window advance
            eq = en * en;
            const int nb = ((t - 1) >> 6) + 1;
            if (nb < S_LEN / 64) en = row[nb * 64 + lane];
        }
        const float e2 = rlane(eq, idx);

        f32x2 A0; A0.x = fmaf(e2, wih0, basb); A0.y = 0.f;
        f32x2 A1 = {0.f, 0.f}, A2 = {0.f, 0.f}, A3 = {0.f, 0.f};
        MV4(0,  w0,  A0, A1) MV4(1,  w1,  A2, A3)
        MV4(2,  w2,  A0, A1) MV4(3,  w3,  A2, A3)
        MV4(4,  w4,  A0, A1) MV4(5,  w5,  A2, A3)
        MV4(6,  w6,  A0, A1) MV4(7,  w7,  A2, A3)
        MV4(8,  w8,  A0, A1) MV4(9,  w9,  A2, A3)
        MV4(10, w10, A0, A1) MV4(11, w11, A2, A3)
        MV4(12, w12, A0, A1) MV4(13, w13, A2, A3)
        MV4(14, w14, A0, A1) MV4(15, w15, A2, A3)
        const f32x2 As = (A0 + A1) + (A2 + A3);
        // sigma (prev step) enters last -> its chain hid under the fma issue
        const float h = fmaf(sigma, wih1, As.x + As.y);

        // write h for next step NOW; LDS latency overlaps wave_sum+softplus
        hbw[lane] = h;

        // x = fc . h + fc_b  (uniform scalar in all lanes)
        const float x = wave_sum(fw * h) + fb;

        // softplus(x) = max(x,0) + log(1 + exp(-|x|)) via v_exp/v_log
        const float e = __expf(-fabsf(x));
        sigma = fmaxf(x, 0.f) + __logf(1.0f + e) + 1e-6f;

        // stage sigma_t into lane (t&63); coalesced store each 64 steps
        if ((t & 63) == lane) vout = sigma;
        if ((t & 63) == 63) orow[(t - 63) + lane] = vout;
    }
#undef MV4
}

extern "C" void kernel_launch(void* const* d_in, const int* in_sizes, int n_in,
                              void* d_out, int out_size, void* d_ws, size_t ws_size,
                              hipStream_t stream) {
    const float* res = (const float*)d_in[0];
    const float* Wih = (const float*)d_in[1];
    const float* bih = (const float*)d_in[2];
    const float* Whh = (const float*)d_in[3];
    const float* bhh = (const float*)d_in[4];
    const float* fcw = (const float*)d_in[5];
    const float* fcb = (const float*)d_in[6];
    float* out = (float*)d_out;

    const int B = 2048;
    dim3 grid(B / 4), block(256);
    hipLaunchKernelGGL(rnn_garch_kernel, grid, block, 0, stream,
                       res, Wih, bih, Whh, bhh, fcw, fcb, out);
}